// Round 10
// baseline (224.060 us; speedup 1.0000x reference)
//
#include <hip/hip_runtime.h>

typedef _Float16 half8 __attribute__((ext_vector_type(8)));
typedef _Float16 half4v __attribute__((ext_vector_type(4)));
typedef __fp16 fp16x2 __attribute__((ext_vector_type(2)));
typedef float f32x16 __attribute__((ext_vector_type(16)));
typedef float f32x4 __attribute__((ext_vector_type(4)));
typedef unsigned int uint2v __attribute__((ext_vector_type(2)));
typedef unsigned int uint4v __attribute__((ext_vector_type(4)));

#define MFMA16(a, b, c) __builtin_amdgcn_mfma_f32_32x32x16_f16((a), (b), (c), 0, 0, 0)
#define QSC 1.44269504088896f  // 1/ln2: Q pre-scaled so logits are in log2 units

// ---------------- workspace layout (bytes) ----------------
#define OFF_WB   0          // wv B-frag [kc16][ct8][lane64][j8] f16      131072
#define OFF_WQK  131072     // wq|wk B-frag [kc16][lane64][j8] f16         16384
#define OFF_QF   147456     // [B*4096][16] f16 (pre-scaled by QSC)       524288
#define OFF_KF   671744     // [B*4096][16] f16                           524288
#define OFF_VB   1196032    // [B][k16:256][ct:8][lane:64][j:8] f16      8388608
#define OFF_MLP  9584640    // [B*4096][kh:2] float2 (m, l)               262144

__device__ inline unsigned int pkf16(float a, float b) {
    union { fp16x2 h; unsigned int u; } cv;
    cv.h = __builtin_amdgcn_cvt_pkrtz(a, b);
    return cv.u;
}
__device__ inline half8 mk8(unsigned int w0, unsigned int w1, unsigned int w2, unsigned int w3) {
    union { unsigned int u[4]; half8 h; } cv;
    cv.u[0] = w0; cv.u[1] = w1; cv.u[2] = w2; cv.u[3] = w3; return cv.h;
}

// ---------------- K0: weight repack ----------------
__global__ __launch_bounds__(256) void k_prep(const float* __restrict__ wq,
                                              const float* __restrict__ wk,
                                              const float* __restrict__ wv,
                                              _Float16* __restrict__ WB,
                                              _Float16* __restrict__ WQK) {
    int idx = blockIdx.x * 256 + threadIdx.x;
    if (idx < 65536) {  // WB: idx = ((kc*8+ct)*64+l)*8+j
        int j = idx & 7, l = (idx >> 3) & 63, kc = idx >> 12;
        int ct = (idx >> 9) & 7;
        int k = kc * 16 + (l >> 5) * 8 + j;
        int c = ct * 32 + (l & 31);
        WB[idx] = (_Float16)wv[k * 256 + c];
    } else if (idx < 65536 + 8192) {  // WQK
        int t = idx - 65536;
        int j = t & 7, l = (t >> 3) & 63, kc = t >> 9;
        int k = kc * 16 + (l >> 5) * 8 + j;
        int c = l & 31;
        WQK[t] = (_Float16)((c < 16) ? wq[k * 16 + c] : wk[k * 16 + (c - 16)]);
    }
}

// ---------------- K1: QKV projection ----------------
__global__ __launch_bounds__(256, 2) void k_proj(const float* __restrict__ x,
                                                 const float* __restrict__ bq,
                                                 const float* __restrict__ bk,
                                                 const float* __restrict__ bv,
                                                 const _Float16* __restrict__ WB,
                                                 const _Float16* __restrict__ WQK,
                                                 _Float16* __restrict__ Qf,
                                                 _Float16* __restrict__ Kf,
                                                 _Float16* __restrict__ VB) {
    const int tid = threadIdx.x;
    const int w = tid >> 6, l = tid & 63, lo = l & 31, h = l >> 5;
    const long rowbase = (long)blockIdx.x * 32;
    const float* xp = x + (rowbase + lo) * 256 + h * 8;

    f32x16 acc0 = {}, acc1 = {}, accQK = {};
#pragma unroll
    for (int kc = 0; kc < 16; ++kc) {
        float4 a0 = *(const float4*)(xp + kc * 16);
        float4 a1 = *(const float4*)(xp + kc * 16 + 4);
        half8 xf;
        xf[0] = (_Float16)a0.x; xf[1] = (_Float16)a0.y; xf[2] = (_Float16)a0.z; xf[3] = (_Float16)a0.w;
        xf[4] = (_Float16)a1.x; xf[5] = (_Float16)a1.y; xf[6] = (_Float16)a1.z; xf[7] = (_Float16)a1.w;
        half8 b0 = *(const half8*)(WB + ((kc * 8 + 2 * w) * 64 + l) * 8);
        half8 b1 = *(const half8*)(WB + ((kc * 8 + 2 * w + 1) * 64 + l) * 8);
        acc0 = MFMA16(xf, b0, acc0);
        acc1 = MFMA16(xf, b1, acc1);
        if (w == 0) {
            half8 bqk = *(const half8*)(WQK + (kc * 64 + l) * 8);
            accQK = MFMA16(xf, bqk, accQK);
        }
    }

    const int b = (int)(rowbase >> 12);
    const int k16base = (int)((rowbase & 4095) >> 4);
#pragma unroll
    for (int cti = 0; cti < 2; ++cti) {
        int ct = 2 * w + cti;
        f32x16 acc = cti ? acc1 : acc0;
        float bias = bv[ct * 32 + lo];
#pragma unroll
        for (int g = 0; g < 4; ++g) {
            int K16 = k16base + (g >> 1);
            int lanep = (g & 1) * 32 + lo;
            _Float16* dst = VB + ((((long)b * 256 + K16) * 8 + ct) * 64 + lanep) * 8 + 4 * h;
            half4v pv;
            pv[0] = (_Float16)(acc[4 * g + 0] + bias);
            pv[1] = (_Float16)(acc[4 * g + 1] + bias);
            pv[2] = (_Float16)(acc[4 * g + 2] + bias);
            pv[3] = (_Float16)(acc[4 * g + 3] + bias);
            *(half4v*)dst = pv;
        }
    }
    if (w == 0) {
        float bias = (lo < 16) ? bq[lo] : bk[lo - 16];
#pragma unroll
        for (int r = 0; r < 16; ++r) {
            int kl = (r & 3) + 8 * (r >> 2) + 4 * h;
            long n = rowbase + kl;
            float v = accQK[r] + bias;
            if (lo < 16) Qf[n * 16 + lo] = (_Float16)(v * QSC);
            else         Kf[n * 16 + (lo - 16)] = (_Float16)v;
        }
    }
}

// ---------------- K2: pass 1 — per-row (m, sum-exp2) over a key half ----------------
__global__ __launch_bounds__(256, 4) void k_ml(const _Float16* __restrict__ Qf,
                                               const _Float16* __restrict__ Kf,
                                               float2* __restrict__ MLp) {
    const int bid = blockIdx.x;            // 1024 = 512 qtiles x 2 key-halves
    const int kh = bid & 1;
    const int qi = bid >> 1;
    const int b = qi >> 7, qt = qi & 127;
    const int tid = threadIdx.x, w = tid >> 6, l = tid & 63, lo = l & 31, h = l >> 5;
    const int qbase = qt * 32;

    half8 qf = *(const half8*)(Qf + (((long)b * 4096 + qbase + lo) << 4) + h * 8);
    const _Float16* Kb = Kf + ((long)b * 4096 << 4);

    float m = -3e38f, lsum = 0.f;
    for (int i = 0; i < 16; ++i) {
        int t = kh * 64 + i * 4 + w;
        half8 kf = *(const half8*)(Kb + ((t * 32 + lo) << 4) + h * 8);
        f32x16 e = MFMA16(kf, qf, (f32x16){});
        float t0 = fmaxf(fmaxf(e[0], e[1]), fmaxf(e[2], e[3]));
        float t1 = fmaxf(fmaxf(e[4], e[5]), fmaxf(e[6], e[7]));
        float t2 = fmaxf(fmaxf(e[8], e[9]), fmaxf(e[10], e[11]));
        float t3 = fmaxf(fmaxf(e[12], e[13]), fmaxf(e[14], e[15]));
        float tmax = fmaxf(fmaxf(t0, t1), fmaxf(t2, t3));
        tmax = fmaxf(tmax, __shfl_xor(tmax, 32));
        if (tmax > m) { lsum *= exp2f(m - tmax); m = tmax; }
        float ss = 0.f;
#pragma unroll
        for (int r = 0; r < 16; ++r) ss += exp2f(e[r] - m);
        lsum += ss;
    }
    lsum += __shfl_xor(lsum, 32);

    __shared__ float sm[4][32];
    __shared__ float sl[4][32];
    if (l < 32) { sm[w][lo] = m; sl[w][lo] = lsum; }
    __syncthreads();
    if (tid < 32) {
        float M = fmaxf(fmaxf(sm[0][tid], sm[1][tid]), fmaxf(sm[2][tid], sm[3][tid]));
        float L = sl[0][tid] * exp2f(sm[0][tid] - M) + sl[1][tid] * exp2f(sm[1][tid] - M) +
                  sl[2][tid] * exp2f(sm[2][tid] - M) + sl[3][tid] * exp2f(sm[3][tid] - M);
        float2 v; v.x = M; v.y = L;
        MLp[(((long)b * 4096 + qbase + tid) << 1) + kh] = v;
    }
}

// ---------------- K3: producer/consumer attention ----------------
// 1024 blocks x 512 threads.  Waves 0-3: compute (QK^T, exp2, pack, stash, PV).
// Waves 4-7: storers — drain the double-buffered fp16 P-cache to HBM
// continuously, overlapping the next compute group.  Split sp owns A-keys
// [sp*2048,(sp+1)*2048) and out0 columns [sp*128,(sp+1)*128).
#define RSg 260  // P-cache row stride in u32 (256 data + 4 skew)
__global__ __launch_bounds__(512, 4) void k_attn(const float* __restrict__ x,
                                                 const float* __restrict__ gptr,
                                                 const _Float16* __restrict__ Qf,
                                                 const _Float16* __restrict__ Kf,
                                                 const _Float16* __restrict__ VB,
                                                 const float2* __restrict__ MLp,
                                                 float* __restrict__ out0,
                                                 float* __restrict__ attn) {
    const int bid = blockIdx.x;                 // 1024 blocks
    const int xcd = bid & 7, slot = bid >> 3;   // batch pinned to XCD pair
    const int b = xcd >> 1;
    const int qt = (xcd & 1) * 64 + (slot & 63);
    const int sp = slot >> 6;                   // 0/1
    const int tid = threadIdx.x;
    const int wv8 = tid >> 6;                   // 0..7
    const bool isComp = wv8 < 4;
    const int w = wv8 & 3;
    const int l = tid & 63, lo = l & 31, h = l >> 5;
    const int qbase = qt * 32;

    // P-cache: double buffer, each 4 iters x 32 rows x 512 keys (fp16 pairs).
    __shared__ unsigned int pc[2][32 * RSg];    // 2 x 33.3 KB

    const _Float16* Kb = Kf + ((long)b * 4096 << 4);
    const _Float16* vb = VB + (long)b * 256 * 8 * 64 * 8;

    // compute-wave state
    half8 qf = {};
    float S_lane = 0.f;
    if (isComp) {
        qf = *(const half8*)(Qf + (((long)b * 4096 + qbase + lo) << 4) + h * 8);
        const float2* mlrow = MLp + ((long)(b * 4096 + qbase + lo) << 1);
        float2 mla = mlrow[0];
        float2 mlc = mlrow[1];
        float Mrow = fmaxf(mla.x, mlc.x);
        S_lane = Mrow + __log2f(mla.y * exp2f(mla.x - Mrow) + mlc.y * exp2f(mlc.x - Mrow));
    }

    // storer-wave mapping
    const int stid = tid & 255;      // waves 4-7 -> 0..255
    const int srow = stid >> 3, st7 = stid & 7;
    float* aoutrow = attn + (long)b * 4096 * 4096 + ((long)(qbase + srow) << 12) + sp * 2048;

    f32x16 oacc[4] = {};

#pragma unroll 1
    for (int g = 0; g < 4; ++g) {
        if (isComp) {
#pragma unroll
            for (int li = 0; li < 4; ++li) {
#pragma unroll
                for (int which = 0; which < 2; ++which) {
                    const bool stash = (which == 0);
                    const int i = (stash ? sp : (1 - sp)) * 16 + g * 4 + li;
                    const int t = i * 4 + w;
                    half8 kf = *(const half8*)(Kb + ((t * 32 + lo) << 4) + h * 8);
                    f32x16 e = MFMA16(kf, qf, (f32x16){});
                    float p[16];
#pragma unroll
                    for (int r = 0; r < 16; ++r) p[r] = exp2f(e[r] - S_lane);

                    unsigned int u0 = pkf16(p[0], p[1]),   x0 = pkf16(p[4], p[5]);
                    unsigned int v0 = pkf16(p[2], p[3]),   y0 = pkf16(p[6], p[7]);
                    unsigned int u1 = pkf16(p[8], p[9]),   x1 = pkf16(p[12], p[13]);
                    unsigned int v1 = pkf16(p[10], p[11]), y1 = pkf16(p[14], p[15]);
                    uint2v t0 = __builtin_amdgcn_permlane32_swap(u0, x0, false, false);
                    uint2v t1 = __builtin_amdgcn_permlane32_swap(v0, y0, false, false);
                    uint2v t2 = __builtin_amdgcn_permlane32_swap(u1, x1, false, false);
                    uint2v t3 = __builtin_amdgcn_permlane32_swap(v1, y1, false, false);
                    half8 pa0 = mk8(t0.x, t1.x, t0.y, t1.y);
                    half8 pa1 = mk8(t2.x, t3.x, t2.y, t3.y);

                    if (stash) {
                        int base = lo * RSg + (li << 6) + (w << 4) + (h << 2);
                        *(uint4v*)&pc[g & 1][base]     = (uint4v){t0.x, t1.x, t0.y, t1.y};
                        *(uint4v*)&pc[g & 1][base + 8] = (uint4v){t2.x, t3.x, t2.y, t3.y};
                    }

#pragma unroll
                    for (int ct = 0; ct < 4; ++ct) {
                        int ctg = 4 * sp + ct;
                        half8 vf0 = *(const half8*)(vb + (((long)(2 * t + 0) * 8 + ctg) * 64 + l) * 8);
                        half8 vf1 = *(const half8*)(vb + (((long)(2 * t + 1) * 8 + ctg) * 64 + l) * 8);
                        oacc[ct] = MFMA16(pa0, vf0, oacc[ct]);
                        oacc[ct] = MFMA16(pa1, vf1, oacc[ct]);
                    }
                }
            }
        } else if (g > 0) {
            // drain group g-1 from pc[(g-1)&1]: each thread expands one row's
            // 2 KB span (16 sequential f32x4 per 128B sector with 7 peers).
            const unsigned int* src = &pc[(g - 1) & 1][srow * RSg + st7 * 2];
            float* ap = aoutrow + (g - 1) * 512 + st7 * 4;
#pragma unroll
            for (int seg = 0; seg < 16; ++seg) {
                uint2v u = *(const uint2v*)(src + seg * 16);
                union { unsigned int u; fp16x2 h; } ua, uc;
                ua.u = u.x; uc.u = u.y;
                f32x4 ov = { (float)ua.h[0], (float)ua.h[1], (float)uc.h[0], (float)uc.h[1] };
                *(f32x4*)(ap + seg * 32) = ov;
            }
        }
        __syncthreads();
    }

    // final drain (group 3) by storers while compute waves wait at merge barrier
    if (!isComp) {
        const unsigned int* src = &pc[1][srow * RSg + st7 * 2];
        float* ap = aoutrow + 3 * 512 + st7 * 4;
#pragma unroll
        for (int seg = 0; seg < 16; ++seg) {
            uint2v u = *(const uint2v*)(src + seg * 16);
            union { unsigned int u; fp16x2 h; } ua, uc;
            ua.u = u.x; uc.u = u.y;
            f32x4 ov = { (float)ua.h[0], (float)ua.h[1], (float)uc.h[0], (float)uc.h[1] };
            *(f32x4*)(ap + seg * 32) = ov;
        }
    }

    // ---- cross-wave O merge into fO (aliases pc[0], already drained) ----
    float* fO = (float*)&pc[0][0];   // [32][132] f32
#pragma unroll 1
    for (int ww = 0; ww < 4; ++ww) {
        __syncthreads();
        if (isComp && w == ww) {
#pragma unroll
            for (int ct = 0; ct < 4; ++ct) {
#pragma unroll
                for (int r = 0; r < 16; ++r) {
                    int row = (r & 3) + 8 * (r >> 2) + 4 * h;
                    float val = oacc[ct][r];
                    if (ww == 0) fO[row * 132 + ct * 32 + lo] = val;
                    else         fO[row * 132 + ct * 32 + lo] += val;
                }
            }
        }
    }
    __syncthreads();

    // ---- epilogue (storer waves): out0 = gamma*O + x for this column half ----
    if (!isComp) {
        float gamma = *gptr;
        int cb = st7 << 4;
        long base = ((long)b * 4096 + qbase + srow) * 256 + sp * 128 + cb;
        const float* xp = x + base;
        float* op = out0 + base;
#pragma unroll
        for (int c0 = 0; c0 < 16; c0 += 4) {
            float4 xv = *(const float4*)(xp + c0);
            f32x4 ov;
            ov.x = gamma * fO[srow * 132 + cb + c0 + 0] + xv.x;
            ov.y = gamma * fO[srow * 132 + cb + c0 + 1] + xv.y;
            ov.z = gamma * fO[srow * 132 + cb + c0 + 2] + xv.z;
            ov.w = gamma * fO[srow * 132 + cb + c0 + 3] + xv.w;
            *(f32x4*)(op + c0) = ov;
        }
    }
}

extern "C" void kernel_launch(void* const* d_in, const int* in_sizes, int n_in,
                              void* d_out, int out_size, void* d_ws, size_t ws_size,
                              hipStream_t stream) {
    const float* x  = (const float*)d_in[0];
    const float* wq = (const float*)d_in[1];
    const float* bq = (const float*)d_in[2];
    const float* wk = (const float*)d_in[3];
    const float* bk = (const float*)d_in[4];
    const float* wv = (const float*)d_in[5];
    const float* bv = (const float*)d_in[6];
    const float* gamma = (const float*)d_in[7];

    char* ws = (char*)d_ws;
    _Float16* WB  = (_Float16*)(ws + OFF_WB);
    _Float16* WQK = (_Float16*)(ws + OFF_WQK);
    _Float16* Qf  = (_Float16*)(ws + OFF_QF);
    _Float16* Kf  = (_Float16*)(ws + OFF_KF);
    _Float16* VB  = (_Float16*)(ws + OFF_VB);
    float2*   MLp = (float2*)(ws + OFF_MLP);

    float* out0 = (float*)d_out;
    float* attn = (float*)d_out + 4194304;  // B*H*W*C

    k_prep<<<288, 256, 0, stream>>>(wq, wk, wv, WB, WQK);
    k_proj<<<512, 256, 0, stream>>>(x, bq, bk, bv, WB, WQK, Qf, Kf, VB);
    k_ml  <<<1024, 256, 0, stream>>>(Qf, Kf, MLp);
    k_attn<<<1024, 512, 0, stream>>>(x, gamma, Qf, Kf, VB, MLp, out0, attn);
}

// Round 11
// 205.440 us; speedup vs baseline: 1.0906x; 1.0906x over previous
//
#include <hip/hip_runtime.h>

typedef _Float16 half8 __attribute__((ext_vector_type(8)));
typedef _Float16 half4v __attribute__((ext_vector_type(4)));
typedef __fp16 fp16x2 __attribute__((ext_vector_type(2)));
typedef float f32x16 __attribute__((ext_vector_type(16)));
typedef float f32x4 __attribute__((ext_vector_type(4)));
typedef unsigned int uint2v __attribute__((ext_vector_type(2)));
typedef unsigned int uint4v __attribute__((ext_vector_type(4)));

#define MFMA16(a, b, c) __builtin_amdgcn_mfma_f32_32x32x16_f16((a), (b), (c), 0, 0, 0)
#define QSC 1.44269504088896f  // 1/ln2: Q pre-scaled so logits are in log2 units

// ---------------- workspace layout (bytes) ----------------
#define OFF_WB   0          // wv B-frag [kc16][ct8][lane64][j8] f16      131072
#define OFF_WQK  131072     // wq|wk B-frag [kc16][lane64][j8] f16         16384
#define OFF_QF   147456     // [B*4096][16] f16 (pre-scaled by QSC)       524288
#define OFF_KF   671744     // [B*4096][16] f16                           524288
#define OFF_VB   1196032    // [B][k16:256][ct:8][lane:64][j:8] f16      8388608
#define OFF_MLP  9584640    // [B*4096][kh:2] float2 (m, l)               262144
#define OFF_PF   16777216   // packed fp16 P: [B*128 qt][G:8][row:32][256 u32] 134217728

__device__ inline unsigned int pkf16(float a, float b) {
    union { fp16x2 h; unsigned int u; } cv;
    cv.h = __builtin_amdgcn_cvt_pkrtz(a, b);
    return cv.u;
}
__device__ inline half8 mk8(unsigned int w0, unsigned int w1, unsigned int w2, unsigned int w3) {
    union { unsigned int u[4]; half8 h; } cv;
    cv.u[0] = w0; cv.u[1] = w1; cv.u[2] = w2; cv.u[3] = w3; return cv.h;
}

// ---------------- K0: weight repack ----------------
__global__ __launch_bounds__(256) void k_prep(const float* __restrict__ wq,
                                              const float* __restrict__ wk,
                                              const float* __restrict__ wv,
                                              _Float16* __restrict__ WB,
                                              _Float16* __restrict__ WQK) {
    int idx = blockIdx.x * 256 + threadIdx.x;
    if (idx < 65536) {  // WB: idx = ((kc*8+ct)*64+l)*8+j
        int j = idx & 7, l = (idx >> 3) & 63, kc = idx >> 12;
        int ct = (idx >> 9) & 7;
        int k = kc * 16 + (l >> 5) * 8 + j;
        int c = ct * 32 + (l & 31);
        WB[idx] = (_Float16)wv[k * 256 + c];
    } else if (idx < 65536 + 8192) {  // WQK
        int t = idx - 65536;
        int j = t & 7, l = (t >> 3) & 63, kc = t >> 9;
        int k = kc * 16 + (l >> 5) * 8 + j;
        int c = l & 31;
        WQK[t] = (_Float16)((c < 16) ? wq[k * 16 + c] : wk[k * 16 + (c - 16)]);
    }
}

// ---------------- K1: QKV projection ----------------
__global__ __launch_bounds__(256, 2) void k_proj(const float* __restrict__ x,
                                                 const float* __restrict__ bq,
                                                 const float* __restrict__ bk,
                                                 const float* __restrict__ bv,
                                                 const _Float16* __restrict__ WB,
                                                 const _Float16* __restrict__ WQK,
                                                 _Float16* __restrict__ Qf,
                                                 _Float16* __restrict__ Kf,
                                                 _Float16* __restrict__ VB) {
    const int tid = threadIdx.x;
    const int w = tid >> 6, l = tid & 63, lo = l & 31, h = l >> 5;
    const long rowbase = (long)blockIdx.x * 32;
    const float* xp = x + (rowbase + lo) * 256 + h * 8;

    f32x16 acc0 = {}, acc1 = {}, accQK = {};
#pragma unroll
    for (int kc = 0; kc < 16; ++kc) {
        float4 a0 = *(const float4*)(xp + kc * 16);
        float4 a1 = *(const float4*)(xp + kc * 16 + 4);
        half8 xf;
        xf[0] = (_Float16)a0.x; xf[1] = (_Float16)a0.y; xf[2] = (_Float16)a0.z; xf[3] = (_Float16)a0.w;
        xf[4] = (_Float16)a1.x; xf[5] = (_Float16)a1.y; xf[6] = (_Float16)a1.z; xf[7] = (_Float16)a1.w;
        half8 b0 = *(const half8*)(WB + ((kc * 8 + 2 * w) * 64 + l) * 8);
        half8 b1 = *(const half8*)(WB + ((kc * 8 + 2 * w + 1) * 64 + l) * 8);
        acc0 = MFMA16(xf, b0, acc0);
        acc1 = MFMA16(xf, b1, acc1);
        if (w == 0) {
            half8 bqk = *(const half8*)(WQK + (kc * 64 + l) * 8);
            accQK = MFMA16(xf, bqk, accQK);
        }
    }

    const int b = (int)(rowbase >> 12);
    const int k16base = (int)((rowbase & 4095) >> 4);
#pragma unroll
    for (int cti = 0; cti < 2; ++cti) {
        int ct = 2 * w + cti;
        f32x16 acc = cti ? acc1 : acc0;
        float bias = bv[ct * 32 + lo];
#pragma unroll
        for (int g = 0; g < 4; ++g) {
            int K16 = k16base + (g >> 1);
            int lanep = (g & 1) * 32 + lo;
            _Float16* dst = VB + ((((long)b * 256 + K16) * 8 + ct) * 64 + lanep) * 8 + 4 * h;
            half4v pv;
            pv[0] = (_Float16)(acc[4 * g + 0] + bias);
            pv[1] = (_Float16)(acc[4 * g + 1] + bias);
            pv[2] = (_Float16)(acc[4 * g + 2] + bias);
            pv[3] = (_Float16)(acc[4 * g + 3] + bias);
            *(half4v*)dst = pv;
        }
    }
    if (w == 0) {
        float bias = (lo < 16) ? bq[lo] : bk[lo - 16];
#pragma unroll
        for (int r = 0; r < 16; ++r) {
            int kl = (r & 3) + 8 * (r >> 2) + 4 * h;
            long n = rowbase + kl;
            float v = accQK[r] + bias;
            if (lo < 16) Qf[n * 16 + lo] = (_Float16)(v * QSC);
            else         Kf[n * 16 + (lo - 16)] = (_Float16)v;
        }
    }
}

// ---------------- K2: pass 1 — per-row (m, sum-exp2) over a key half ----------------
__global__ __launch_bounds__(256, 4) void k_ml(const _Float16* __restrict__ Qf,
                                               const _Float16* __restrict__ Kf,
                                               float2* __restrict__ MLp) {
    const int bid = blockIdx.x;            // 1024 = 512 qtiles x 2 key-halves
    const int kh = bid & 1;
    const int qi = bid >> 1;
    const int b = qi >> 7, qt = qi & 127;
    const int tid = threadIdx.x, w = tid >> 6, l = tid & 63, lo = l & 31, h = l >> 5;
    const int qbase = qt * 32;

    half8 qf = *(const half8*)(Qf + (((long)b * 4096 + qbase + lo) << 4) + h * 8);
    const _Float16* Kb = Kf + ((long)b * 4096 << 4);

    float m = -3e38f, lsum = 0.f;
    for (int i = 0; i < 16; ++i) {
        int t = kh * 64 + i * 4 + w;
        half8 kf = *(const half8*)(Kb + ((t * 32 + lo) << 4) + h * 8);
        f32x16 e = MFMA16(kf, qf, (f32x16){});
        float t0 = fmaxf(fmaxf(e[0], e[1]), fmaxf(e[2], e[3]));
        float t1 = fmaxf(fmaxf(e[4], e[5]), fmaxf(e[6], e[7]));
        float t2 = fmaxf(fmaxf(e[8], e[9]), fmaxf(e[10], e[11]));
        float t3 = fmaxf(fmaxf(e[12], e[13]), fmaxf(e[14], e[15]));
        float tmax = fmaxf(fmaxf(t0, t1), fmaxf(t2, t3));
        tmax = fmaxf(tmax, __shfl_xor(tmax, 32));
        if (tmax > m) { lsum *= exp2f(m - tmax); m = tmax; }
        float ss = 0.f;
#pragma unroll
        for (int r = 0; r < 16; ++r) ss += exp2f(e[r] - m);
        lsum += ss;
    }
    lsum += __shfl_xor(lsum, 32);

    __shared__ float sm[4][32];
    __shared__ float sl[4][32];
    if (l < 32) { sm[w][lo] = m; sl[w][lo] = lsum; }
    __syncthreads();
    if (tid < 32) {
        float M = fmaxf(fmaxf(sm[0][tid], sm[1][tid]), fmaxf(sm[2][tid], sm[3][tid]));
        float L = sl[0][tid] * exp2f(sm[0][tid] - M) + sl[1][tid] * exp2f(sm[1][tid] - M) +
                  sl[2][tid] * exp2f(sm[2][tid] - M) + sl[3][tid] * exp2f(sm[3][tid] - M);
        float2 v; v.x = M; v.y = L;
        MLp[(((long)b * 4096 + qbase + tid) << 1) + kh] = v;
    }
}

// ---------------- K3: attention — PV + compact fp16 P write (no A-write) ----------------
// 1024 blocks = 4 batches x 128 qtiles x 2 splits.  Split sp owns:
//   Pf groups G = sp*4..sp*4+3 (keys [sp*2048,(sp+1)*2048))   (iters i>>4 == sp)
//   PV + out0 for columns [sp*128, (sp+1)*128)
// Pf layout: [(b*128+qt)][G:8][row:32][256 u32]  (u32 = fp16 key-pair, keys ascending)
#define RSg 260  // P-cache row stride in u32 (256 data + 4 skew)
__global__ __launch_bounds__(256, 4) void k_attn(const float* __restrict__ x,
                                                 const float* __restrict__ gptr,
                                                 const _Float16* __restrict__ Qf,
                                                 const _Float16* __restrict__ Kf,
                                                 const _Float16* __restrict__ VB,
                                                 const float2* __restrict__ MLp,
                                                 float* __restrict__ out0,
                                                 unsigned int* __restrict__ Pf) {
    const int bid = blockIdx.x;                 // 1024 blocks
    const int xcd = bid & 7, slot = bid >> 3;   // batch pinned to XCD pair
    const int b = xcd >> 1;
    const int qt = (xcd & 1) * 64 + (slot & 63);
    const int sp = slot >> 6;                   // 0/1
    const int tid = threadIdx.x, w = tid >> 6, l = tid & 63, lo = l & 31, h = l >> 5;
    const int qbase = qt * 32;

    half8 qf = *(const half8*)(Qf + (((long)b * 4096 + qbase + lo) << 4) + h * 8);
    const _Float16* Kb = Kf + ((long)b * 4096 << 4);

    // combine the two key-half (m,l) partials -> S = M + log2(L)
    const float2* mlrow = MLp + ((long)(b * 4096 + qbase + lo) << 1);
    float2 mla = mlrow[0];
    float2 mlc = mlrow[1];
    float Mrow = fmaxf(mla.x, mlc.x);
    const float S_lane = Mrow + __log2f(mla.y * exp2f(mla.x - Mrow) + mlc.y * exp2f(mlc.x - Mrow));

    const _Float16* vb = VB + (long)b * 256 * 8 * 64 * 8;

    // P-cache: one group (4 iters) x 32 rows x 512 keys as fp16 pairs (~33 KB).
    // Reused as f32 [32][132] tile for the O-merge afterwards.
    __shared__ unsigned int pc[32 * RSg];

    unsigned int* PfT = Pf + (long)(b * 128 + qt) * 8 * 8192;  // + G*8192

    f32x16 oacc[4] = {};

    for (int i = 0; i < 32; ++i) {
        int t = i * 4 + w;
        half8 kf = *(const half8*)(Kb + ((t * 32 + lo) << 4) + h * 8);
        f32x16 e = MFMA16(kf, qf, (f32x16){});
        float p[16];
#pragma unroll
        for (int r = 0; r < 16; ++r) p[r] = exp2f(e[r] - S_lane);

        // pack p -> fp16 A-fragments (PV operand; also the stored P values)
        unsigned int u0 = pkf16(p[0], p[1]),   x0 = pkf16(p[4], p[5]);
        unsigned int v0 = pkf16(p[2], p[3]),   y0 = pkf16(p[6], p[7]);
        unsigned int u1 = pkf16(p[8], p[9]),   x1 = pkf16(p[12], p[13]);
        unsigned int v1 = pkf16(p[10], p[11]), y1 = pkf16(p[14], p[15]);
        uint2v t0 = __builtin_amdgcn_permlane32_swap(u0, x0, false, false);
        uint2v t1 = __builtin_amdgcn_permlane32_swap(v0, y0, false, false);
        uint2v t2 = __builtin_amdgcn_permlane32_swap(u1, x1, false, false);
        uint2v t3 = __builtin_amdgcn_permlane32_swap(v1, y1, false, false);
        half8 pa0 = mk8(t0.x, t1.x, t0.y, t1.y);
        half8 pa1 = mk8(t2.x, t3.x, t2.y, t3.y);

        // --- stash packed fp16 P; flush each 4-iter group contiguously to Pf ---
        if ((i >> 4) == sp) {
            int li = i & 3;
            int base = lo * RSg + (li << 6) + (w << 4) + (h << 2);
            *(uint4v*)&pc[base]     = (uint4v){t0.x, t1.x, t0.y, t1.y};
            *(uint4v*)&pc[base + 8] = (uint4v){t2.x, t3.x, t2.y, t3.y};
            if (li == 3) {
                __syncthreads();   // cache fully written
                // contiguous 32 KB flush: inst `it` = 1 KB sequential (64 lanes x 16B)
                int G = sp * 4 + ((i >> 2) & 3);
                unsigned int* dst = PfT + (long)G * 8192;
#pragma unroll
                for (int it = 0; it < 8; ++it) {
                    uint4v v = *(const uint4v*)&pc[(it * 4 + w) * RSg + l * 4];
                    *(uint4v*)(dst + it * 1024 + w * 256 + l * 4) = v;
                }
                __syncthreads();   // flush done before next group's stash
            }
        }

        // --- PV for this block's column half ---
#pragma unroll
        for (int ct = 0; ct < 4; ++ct) {
            int ctg = 4 * sp + ct;
            half8 vf0 = *(const half8*)(vb + (((long)(2 * t + 0) * 8 + ctg) * 64 + l) * 8);
            half8 vf1 = *(const half8*)(vb + (((long)(2 * t + 1) * 8 + ctg) * 64 + l) * 8);
            oacc[ct] = MFMA16(pa0, vf0, oacc[ct]);
            oacc[ct] = MFMA16(pa1, vf1, oacc[ct]);
        }
    }

    // ---- cross-wave O merge (key-split) + epilogue for this column half ----
    float* fO = (float*)pc;   // reuse as [32][132] f32 tile
#pragma unroll 1
    for (int ww = 0; ww < 4; ++ww) {
        __syncthreads();
        if (w == ww) {
#pragma unroll
            for (int ct = 0; ct < 4; ++ct) {
#pragma unroll
                for (int r = 0; r < 16; ++r) {
                    int row = (r & 3) + 8 * (r >> 2) + 4 * h;
                    float val = oacc[ct][r];
                    if (ww == 0) fO[row * 132 + ct * 32 + lo] = val;
                    else         fO[row * 132 + ct * 32 + lo] += val;
                }
            }
        }
    }
    __syncthreads();

    float gamma = *gptr;
    const int srow = tid >> 3, st7 = tid & 7;
    int cb = st7 << 4;  // 16 cols per thread within the 128-col half
    long base = ((long)b * 4096 + qbase + srow) * 256 + sp * 128 + cb;
    const float* xp = x + base;
    float* op = out0 + base;
#pragma unroll
    for (int c0 = 0; c0 < 16; c0 += 4) {
        float4 xv = *(const float4*)(xp + c0);
        f32x4 ov;
        ov.x = gamma * fO[srow * 132 + cb + c0 + 0] + xv.x;
        ov.y = gamma * fO[srow * 132 + cb + c0 + 1] + xv.y;
        ov.z = gamma * fO[srow * 132 + cb + c0 + 2] + xv.z;
        ov.w = gamma * fO[srow * 132 + cb + c0 + 3] + xv.w;
        *(f32x4*)(op + c0) = ov;
    }
}

// ---------------- K4: Pf (fp16) -> attn (f32), fill-shaped streaming ----------------
// 1024 blocks: (b, qt, half).  Each block expands 16 q-rows x 4096 keys = 256 KB,
// written in ascending order; every store instruction is 1 KB contiguous.
__global__ __launch_bounds__(256) void k_expand(const unsigned int* __restrict__ Pf,
                                                float* __restrict__ attn) {
    const int bid = blockIdx.x;               // 1024
    const int b = bid >> 8, qt = (bid >> 1) & 127, half = bid & 1;
    const int tid = threadIdx.x, w = tid >> 6, l = tid & 63;
    const unsigned int* PfT = Pf + (long)(b * 128 + qt) * 8 * 8192;
    float* abase = attn + (long)b * 4096 * 4096 + (long)(qt * 32) * 4096;

#pragma unroll 1
    for (int rr = 0; rr < 4; ++rr) {
        int r = half * 16 + w * 4 + rr;
        float* arow = abase + (long)r * 4096;
        const unsigned int* prow = PfT + r * 256;
#pragma unroll
        for (int j = 0; j < 16; ++j) {
            int k = j * 256 + l * 4;
            int G = k >> 9;
            int offw = ((k & 511) >> 1);      // u32 offset within row
            uint2v u = *(const uint2v*)(prow + (long)G * 8192 + offw);
            union { unsigned int u; fp16x2 h; } ua, uc;
            ua.u = u.x; uc.u = u.y;
            f32x4 ov = { (float)ua.h[0], (float)ua.h[1], (float)uc.h[0], (float)uc.h[1] };
            *(f32x4*)(arow + k) = ov;
        }
    }
}

extern "C" void kernel_launch(void* const* d_in, const int* in_sizes, int n_in,
                              void* d_out, int out_size, void* d_ws, size_t ws_size,
                              hipStream_t stream) {
    const float* x  = (const float*)d_in[0];
    const float* wq = (const float*)d_in[1];
    const float* bq = (const float*)d_in[2];
    const float* wk = (const float*)d_in[3];
    const float* bk = (const float*)d_in[4];
    const float* wv = (const float*)d_in[5];
    const float* bv = (const float*)d_in[6];
    const float* gamma = (const float*)d_in[7];

    char* ws = (char*)d_ws;
    _Float16* WB  = (_Float16*)(ws + OFF_WB);
    _Float16* WQK = (_Float16*)(ws + OFF_WQK);
    _Float16* Qf  = (_Float16*)(ws + OFF_QF);
    _Float16* Kf  = (_Float16*)(ws + OFF_KF);
    _Float16* VB  = (_Float16*)(ws + OFF_VB);
    float2*   MLp = (float2*)(ws + OFF_MLP);
    unsigned int* Pf = (unsigned int*)(ws + OFF_PF);

    float* out0 = (float*)d_out;
    float* attn = (float*)d_out + 4194304;  // B*H*W*C

    k_prep  <<<288, 256, 0, stream>>>(wq, wk, wv, WB, WQK);
    k_proj  <<<512, 256, 0, stream>>>(x, bq, bk, bv, WB, WQK, Qf, Kf, VB);
    k_ml    <<<1024, 256, 0, stream>>>(Qf, Kf, MLp);
    k_attn  <<<1024, 256, 0, stream>>>(x, gamma, Qf, Kf, VB, MLp, out0, Pf);
    k_expand<<<1024, 256, 0, stream>>>(Pf, attn);
}

// Round 12
// 144.374 us; speedup vs baseline: 1.5519x; 1.4230x over previous
//
#include <hip/hip_runtime.h>

typedef _Float16 half8 __attribute__((ext_vector_type(8)));
typedef _Float16 half4v __attribute__((ext_vector_type(4)));
typedef __fp16 fp16x2 __attribute__((ext_vector_type(2)));
typedef float f32x16 __attribute__((ext_vector_type(16)));
typedef float f32x4 __attribute__((ext_vector_type(4)));
typedef unsigned int uint2v __attribute__((ext_vector_type(2)));

#define MFMA16(a, b, c) __builtin_amdgcn_mfma_f32_32x32x16_f16((a), (b), (c), 0, 0, 0)
#define QSC 1.44269504088896f  // 1/ln2: Q pre-scaled so logits are in log2 units

// ---------------- workspace layout (bytes) ----------------
#define OFF_WB   0          // wv B-frag [kc16][ct8][lane64][j8] f16      131072
#define OFF_WQK  131072     // wq|wk B-frag [kc16][lane64][j8] f16         16384
#define OFF_QF   147456     // [B*4096][16] f16 (pre-scaled by QSC)       524288
#define OFF_KF   671744     // [B*4096][16] f16                           524288
#define OFF_VB   1196032    // [B][k16:256][ct:8][lane:64][j:8] f16      8388608
#define OFF_MLP  9584640    // [B*4096][kh:2] float2 (m, l)               262144

__device__ inline unsigned int pkf16(float a, float b) {
    union { fp16x2 h; unsigned int u; } cv;
    cv.h = __builtin_amdgcn_cvt_pkrtz(a, b);
    return cv.u;
}
__device__ inline half8 mk8(unsigned int w0, unsigned int w1, unsigned int w2, unsigned int w3) {
    union { unsigned int u[4]; half8 h; } cv;
    cv.u[0] = w0; cv.u[1] = w1; cv.u[2] = w2; cv.u[3] = w3; return cv.h;
}

// ---------------- K0: weight repack ----------------
__global__ __launch_bounds__(256) void k_prep(const float* __restrict__ wq,
                                              const float* __restrict__ wk,
                                              const float* __restrict__ wv,
                                              _Float16* __restrict__ WB,
                                              _Float16* __restrict__ WQK) {
    int idx = blockIdx.x * 256 + threadIdx.x;
    if (idx < 65536) {  // WB: idx = ((kc*8+ct)*64+l)*8+j
        int j = idx & 7, l = (idx >> 3) & 63, kc = idx >> 12;
        int ct = (idx >> 9) & 7;
        int k = kc * 16 + (l >> 5) * 8 + j;
        int c = ct * 32 + (l & 31);
        WB[idx] = (_Float16)wv[k * 256 + c];
    } else if (idx < 65536 + 8192) {  // WQK
        int t = idx - 65536;
        int j = t & 7, l = (t >> 3) & 63, kc = t >> 9;
        int k = kc * 16 + (l >> 5) * 8 + j;
        int c = l & 31;
        WQK[t] = (_Float16)((c < 16) ? wq[k * 16 + c] : wk[k * 16 + (c - 16)]);
    }
}

// ---------------- K1: QKV projection ----------------
__global__ __launch_bounds__(256, 2) void k_proj(const float* __restrict__ x,
                                                 const float* __restrict__ bq,
                                                 const float* __restrict__ bk,
                                                 const float* __restrict__ bv,
                                                 const _Float16* __restrict__ WB,
                                                 const _Float16* __restrict__ WQK,
                                                 _Float16* __restrict__ Qf,
                                                 _Float16* __restrict__ Kf,
                                                 _Float16* __restrict__ VB) {
    const int tid = threadIdx.x;
    const int w = tid >> 6, l = tid & 63, lo = l & 31, h = l >> 5;
    const long rowbase = (long)blockIdx.x * 32;
    const float* xp = x + (rowbase + lo) * 256 + h * 8;

    f32x16 acc0 = {}, acc1 = {}, accQK = {};
#pragma unroll
    for (int kc = 0; kc < 16; ++kc) {
        float4 a0 = *(const float4*)(xp + kc * 16);
        float4 a1 = *(const float4*)(xp + kc * 16 + 4);
        half8 xf;
        xf[0] = (_Float16)a0.x; xf[1] = (_Float16)a0.y; xf[2] = (_Float16)a0.z; xf[3] = (_Float16)a0.w;
        xf[4] = (_Float16)a1.x; xf[5] = (_Float16)a1.y; xf[6] = (_Float16)a1.z; xf[7] = (_Float16)a1.w;
        half8 b0 = *(const half8*)(WB + ((kc * 8 + 2 * w) * 64 + l) * 8);
        half8 b1 = *(const half8*)(WB + ((kc * 8 + 2 * w + 1) * 64 + l) * 8);
        acc0 = MFMA16(xf, b0, acc0);
        acc1 = MFMA16(xf, b1, acc1);
        if (w == 0) {
            half8 bqk = *(const half8*)(WQK + (kc * 64 + l) * 8);
            accQK = MFMA16(xf, bqk, accQK);
        }
    }

    const int b = (int)(rowbase >> 12);
    const int k16base = (int)((rowbase & 4095) >> 4);
#pragma unroll
    for (int cti = 0; cti < 2; ++cti) {
        int ct = 2 * w + cti;
        f32x16 acc = cti ? acc1 : acc0;
        float bias = bv[ct * 32 + lo];
#pragma unroll
        for (int g = 0; g < 4; ++g) {
            int K16 = k16base + (g >> 1);
            int lanep = (g & 1) * 32 + lo;
            _Float16* dst = VB + ((((long)b * 256 + K16) * 8 + ct) * 64 + lanep) * 8 + 4 * h;
            half4v pv;
            pv[0] = (_Float16)(acc[4 * g + 0] + bias);
            pv[1] = (_Float16)(acc[4 * g + 1] + bias);
            pv[2] = (_Float16)(acc[4 * g + 2] + bias);
            pv[3] = (_Float16)(acc[4 * g + 3] + bias);
            *(half4v*)dst = pv;
        }
    }
    if (w == 0) {
        float bias = (lo < 16) ? bq[lo] : bk[lo - 16];
#pragma unroll
        for (int r = 0; r < 16; ++r) {
            int kl = (r & 3) + 8 * (r >> 2) + 4 * h;
            long n = rowbase + kl;
            float v = accQK[r] + bias;
            if (lo < 16) Qf[n * 16 + lo] = (_Float16)(v * QSC);
            else         Kf[n * 16 + (lo - 16)] = (_Float16)v;
        }
    }
}

// ---------------- K2: pass 1 — per-row (m, sum-exp2) over a key half ----------------
__global__ __launch_bounds__(256, 4) void k_ml(const _Float16* __restrict__ Qf,
                                               const _Float16* __restrict__ Kf,
                                               float2* __restrict__ MLp) {
    const int bid = blockIdx.x;            // 1024 = 512 qtiles x 2 key-halves
    const int kh = bid & 1;
    const int qi = bid >> 1;
    const int b = qi >> 7, qt = qi & 127;
    const int tid = threadIdx.x, w = tid >> 6, l = tid & 63, lo = l & 31, h = l >> 5;
    const int qbase = qt * 32;

    half8 qf = *(const half8*)(Qf + (((long)b * 4096 + qbase + lo) << 4) + h * 8);
    const _Float16* Kb = Kf + ((long)b * 4096 << 4);

    float m = -3e38f, lsum = 0.f;
    for (int i = 0; i < 16; ++i) {
        int t = kh * 64 + i * 4 + w;
        half8 kf = *(const half8*)(Kb + ((t * 32 + lo) << 4) + h * 8);
        f32x16 e = MFMA16(kf, qf, (f32x16){});
        float t0 = fmaxf(fmaxf(e[0], e[1]), fmaxf(e[2], e[3]));
        float t1 = fmaxf(fmaxf(e[4], e[5]), fmaxf(e[6], e[7]));
        float t2 = fmaxf(fmaxf(e[8], e[9]), fmaxf(e[10], e[11]));
        float t3 = fmaxf(fmaxf(e[12], e[13]), fmaxf(e[14], e[15]));
        float tmax = fmaxf(fmaxf(t0, t1), fmaxf(t2, t3));
        tmax = fmaxf(tmax, __shfl_xor(tmax, 32));
        if (tmax > m) { lsum *= exp2f(m - tmax); m = tmax; }
        float ss = 0.f;
#pragma unroll
        for (int r = 0; r < 16; ++r) ss += exp2f(e[r] - m);
        lsum += ss;
    }
    lsum += __shfl_xor(lsum, 32);

    __shared__ float sm[4][32];
    __shared__ float sl[4][32];
    if (l < 32) { sm[w][lo] = m; sl[w][lo] = lsum; }
    __syncthreads();
    if (tid < 32) {
        float M = fmaxf(fmaxf(sm[0][tid], sm[1][tid]), fmaxf(sm[2][tid], sm[3][tid]));
        float L = sl[0][tid] * exp2f(sm[0][tid] - M) + sl[1][tid] * exp2f(sm[1][tid] - M) +
                  sl[2][tid] * exp2f(sm[2][tid] - M) + sl[3][tid] * exp2f(sm[3][tid] - M);
        float2 v; v.x = M; v.y = L;
        MLp[(((long)b * 4096 + qbase + tid) << 1) + kh] = v;
    }
}

// ---------------- K3: single-pass attention, LDS-staged cached A-store, UNPINNED ----------------
// 1024 blocks, linear decode: sp = bid&1, qt = (bid>>1)&127, b = bid>>8.
// No XCD pinning: each batch's write stream now issues from all 8 XCDs
// (pinning confined each batch's 67+4 MB writes to 2 XCDs' eviction path —
// the invariant shared by every ~146 µs round).  V/K/Q total 9.4 MB: L3-resident.
__global__ __launch_bounds__(256, 4) void k_attn(const float* __restrict__ x,
                                                 const float* __restrict__ gptr,
                                                 const _Float16* __restrict__ Qf,
                                                 const _Float16* __restrict__ Kf,
                                                 const _Float16* __restrict__ VB,
                                                 const float2* __restrict__ MLp,
                                                 float* __restrict__ out0,
                                                 float* __restrict__ attn) {
    const int bid = blockIdx.x;                 // 1024 blocks
    const int sp = bid & 1;                     // key/column half
    const int qt = (bid >> 1) & 127;
    const int b  = bid >> 8;
    const int tid = threadIdx.x, w = tid >> 6, l = tid & 63, lo = l & 31, h = l >> 5;
    const int qbase = qt * 32;

    half8 qf = *(const half8*)(Qf + (((long)b * 4096 + qbase + lo) << 4) + h * 8);
    const _Float16* Kb = Kf + ((long)b * 4096 << 4);

    // combine the two key-half (m,l) partials -> S = M + log2(L)
    const float2* mlrow = MLp + ((long)(b * 4096 + qbase + lo) << 1);
    float2 mla = mlrow[0];
    float2 mlc = mlrow[1];
    float Mrow = fmaxf(mla.x, mlc.x);
    const float S_lane = Mrow + __log2f(mla.y * exp2f(mla.x - Mrow) + mlc.y * exp2f(mlc.x - Mrow));

    const _Float16* vb = VB + (long)b * 256 * 8 * 64 * 8;

    // Staging tile [row 32][col 128] f32, row padded to 132 dwords (528 B).
    // Reused for the O-merge afterwards.
    __shared__ float ldsS[32 * 132];

    // cooperative-store mapping for this thread
    const int srow = tid >> 3;       // 0..31
    const int st7 = tid & 7;         // 16B chunk within 512B row-quarter
    float* aout = attn + (long)b * 4096 * 4096 + ((long)(qbase + srow) << 12) + st7 * 4;

    f32x16 oacc[4] = {};

    for (int i = 0; i < 32; ++i) {
        int t = i * 4 + w;
        half8 kf = *(const half8*)(Kb + ((t * 32 + lo) << 4) + h * 8);
        f32x16 e = MFMA16(kf, qf, (f32x16){});
        float p[16];
#pragma unroll
        for (int r = 0; r < 16; ++r) p[r] = exp2f(e[r] - S_lane);

        // --- A-store via LDS staging (this block's key half only) ---
        // fragment -> LDS natural layout: lane (w,lo,h) reg r=4g+j holds
        // A[row=lo][key-local = w*32 + g*8 + h*4 + j] -> one f32x4 per g.
        if ((i >> 4) == sp) {
            __syncthreads();   // prior reads of ldsS complete
#pragma unroll
            for (int g = 0; g < 4; ++g) {
                f32x4 st = { p[4 * g + 0], p[4 * g + 1], p[4 * g + 2], p[4 * g + 3] };
                *(f32x4*)&ldsS[lo * 132 + w * 32 + g * 8 + h * 4] = st;
            }
            __syncthreads();   // tile fully staged
            // cooperative CACHED store: each wave instruction covers 8 rows x 16B
            // at the same 128B-aligned column -> 8 FULL 128B sectors per instruction.
            float* ap = aout + i * 128;
#pragma unroll
            for (int seg = 0; seg < 4; ++seg) {
                f32x4 v = *(const f32x4*)&ldsS[srow * 132 + seg * 32 + st7 * 4];
                *(f32x4*)(ap + seg * 32) = v;
            }
        }

        // pack p -> fp16 A-fragments (full row needed for PV regardless of split)
        unsigned int u0 = pkf16(p[0], p[1]),   x0 = pkf16(p[4], p[5]);
        unsigned int v0 = pkf16(p[2], p[3]),   y0 = pkf16(p[6], p[7]);
        unsigned int u1 = pkf16(p[8], p[9]),   x1 = pkf16(p[12], p[13]);
        unsigned int v1 = pkf16(p[10], p[11]), y1 = pkf16(p[14], p[15]);
        uint2v t0 = __builtin_amdgcn_permlane32_swap(u0, x0, false, false);
        uint2v t1 = __builtin_amdgcn_permlane32_swap(v0, y0, false, false);
        uint2v t2 = __builtin_amdgcn_permlane32_swap(u1, x1, false, false);
        uint2v t3 = __builtin_amdgcn_permlane32_swap(v1, y1, false, false);
        half8 pa0 = mk8(t0.x, t1.x, t0.y, t1.y);
        half8 pa1 = mk8(t2.x, t3.x, t2.y, t3.y);

#pragma unroll
        for (int ct = 0; ct < 4; ++ct) {
            int ctg = 4 * sp + ct;
            half8 vf0 = *(const half8*)(vb + (((long)(2 * t + 0) * 8 + ctg) * 64 + l) * 8);
            half8 vf1 = *(const half8*)(vb + (((long)(2 * t + 1) * 8 + ctg) * 64 + l) * 8);
            oacc[ct] = MFMA16(pa0, vf0, oacc[ct]);
            oacc[ct] = MFMA16(pa1, vf1, oacc[ct]);
        }
    }

    // ---- cross-wave O merge (key-split) + epilogue for this column half ----
    // reuse ldsS as [32][132]-padded O tile (cols 0..127)
#pragma unroll 1
    for (int ww = 0; ww < 4; ++ww) {
        __syncthreads();
        if (w == ww) {
#pragma unroll
            for (int ct = 0; ct < 4; ++ct) {
#pragma unroll
                for (int r = 0; r < 16; ++r) {
                    int row = (r & 3) + 8 * (r >> 2) + 4 * h;
                    float val = oacc[ct][r];
                    if (ww == 0) ldsS[row * 132 + ct * 32 + lo] = val;
                    else         ldsS[row * 132 + ct * 32 + lo] += val;
                }
            }
        }
    }
    __syncthreads();

    float gamma = *gptr;
    int cb = st7 << 4;  // 16 cols per thread within the 128-col half
    long base = ((long)b * 4096 + qbase + srow) * 256 + sp * 128 + cb;
    const float* xp = x + base;
    float* op = out0 + base;
#pragma unroll
    for (int c0 = 0; c0 < 16; c0 += 4) {
        float4 xv = *(const float4*)(xp + c0);
        f32x4 ov;
        ov.x = gamma * ldsS[srow * 132 + cb + c0 + 0] + xv.x;
        ov.y = gamma * ldsS[srow * 132 + cb + c0 + 1] + xv.y;
        ov.z = gamma * ldsS[srow * 132 + cb + c0 + 2] + xv.z;
        ov.w = gamma * ldsS[srow * 132 + cb + c0 + 3] + xv.w;
        *(f32x4*)(op + c0) = ov;
    }
}

extern "C" void kernel_launch(void* const* d_in, const int* in_sizes, int n_in,
                              void* d_out, int out_size, void* d_ws, size_t ws_size,
                              hipStream_t stream) {
    const float* x  = (const float*)d_in[0];
    const float* wq = (const float*)d_in[1];
    const float* bq = (const float*)d_in[2];
    const float* wk = (const float*)d_in[3];
    const float* bk = (const float*)d_in[4];
    const float* wv = (const float*)d_in[5];
    const float* bv = (const float*)d_in[6];
    const float* gamma = (const float*)d_in[7];

    char* ws = (char*)d_ws;
    _Float16* WB  = (_Float16*)(ws + OFF_WB);
    _Float16* WQK = (_Float16*)(ws + OFF_WQK);
    _Float16* Qf  = (_Float16*)(ws + OFF_QF);
    _Float16* Kf  = (_Float16*)(ws + OFF_KF);
    _Float16* VB  = (_Float16*)(ws + OFF_VB);
    float2*   MLp = (float2*)(ws + OFF_MLP);

    float* out0 = (float*)d_out;
    float* attn = (float*)d_out + 4194304;  // B*H*W*C

    k_prep<<<288, 256, 0, stream>>>(wq, wk, wv, WB, WQK);
    k_proj<<<512, 256, 0, stream>>>(x, bq, bk, bv, WB, WQK, Qf, Kf, VB);
    k_ml  <<<1024, 256, 0, stream>>>(Qf, Kf, MLp);
    k_attn<<<1024, 256, 0, stream>>>(x, gamma, Qf, Kf, VB, MLp, out0, attn);
}